// Round 13
// baseline (503.089 us; speedup 1.0000x reference)
//
#include <hip/hip_runtime.h>
#include <math.h>

#define D_MODEL 1024
#define D_STATE 16
#define D_CONV  4
#define D_INNER 2048
#define DT_RANK 64
#define BATCH   2
#define SEQ     2048
#define M_ROWS  (BATCH * SEQ)   // 4096

#define TC 32                   // scan chunk length
#define NC (SEQ / TC)           // 64 chunks

#define KS  8                   // proj split-K factor
#define KCH (2048 / KS)         // 256

typedef __attribute__((ext_vector_type(8))) short short8;
typedef __attribute__((ext_vector_type(4))) float f32x4;

__device__ __forceinline__ float softplusf(float x) {
    return (x > 20.f) ? x : log1pf(__expf(x));
}
__device__ __forceinline__ float siluf(float x) {
    return x * (1.f / (1.f + __expf(-x)));
}
__device__ __forceinline__ unsigned short f2bf(float f) {   // RNE f32->bf16
    unsigned u = __float_as_uint(f);
    u += 0x7FFFu + ((u >> 16) & 1u);
    return (unsigned short)(u >> 16);
}

// async global->LDS DMA, 16 B per lane; LDS dest = wave-uniform base + lane*16
__device__ __forceinline__ void load_lds16(const void* g, void* l) {
    __builtin_amdgcn_global_load_lds(
        (const __attribute__((address_space(1))) void*)g,
        (__attribute__((address_space(3))) void*)l, 16, 0, 0);
}

// ---------------------------------------------------------------------------
// fp32 -> bf16 elementwise (8 elems/thread)
// ---------------------------------------------------------------------------
__global__ __launch_bounds__(256)
void cvt_f32_bf16(const float* __restrict__ src, unsigned short* __restrict__ dst)
{
    const size_t i = (size_t)(blockIdx.x * 256 + threadIdx.x) * 8;
    const float4 a = *(const float4*)(src + i);
    const float4 b = *(const float4*)(src + i + 4);
    short8 r;
    r[0] = (short)f2bf(a.x); r[1] = (short)f2bf(a.y);
    r[2] = (short)f2bf(a.z); r[3] = (short)f2bf(a.w);
    r[4] = (short)f2bf(b.x); r[5] = (short)f2bf(b.y);
    r[6] = (short)f2bf(b.z); r[7] = (short)f2bf(b.w);
    *(short8*)(dst + i) = r;
}

// ---------------------------------------------------------------------------
// bf16 MFMA GEMM: C(M x N fp32) = A(M x K bf16) @ W(N x K bf16)^T
// BM=BN=128, BK=32; 256 threads = 4 waves (2x2), each wave owns 64x64.
// LDS fragment-linear layout: slot = ((row>>4)*4 + kgroup)*16 + (row&15).
// Staging via global_load_lds width=16: wave w's 64 lanes fill 64 consecutive
// slots (wave-uniform base + lane*16), per-lane GLOBAL address pre-swizzled to
// (row, kgroup) of that slot -- layout identical to the verified Round-7/9 one.
// MFMA 16x16x32 layouts (m89-verified): A: row=l&15, k=(l>>4)*8+e;
// B: col=l&15, k=(l>>4)*8+e; D: col=l&15, row=(l>>4)*4+reg.
// ---------------------------------------------------------------------------
__global__ __launch_bounds__(256, 2)
void gemm_bf16(const unsigned short* __restrict__ A,
               const unsigned short* __restrict__ W,
               float* __restrict__ C, int ldc, int K)
{
    __shared__ short Asl[512 * 8];   // 8 KB
    __shared__ short Wsl[512 * 8];   // 8 KB

    const int tid  = threadIdx.x;
    const int lane = tid & 63;
    const int wv   = tid >> 6;       // 0..3
    const int wm   = wv >> 1;        // wave row (0..1)
    const int wn   = wv & 1;         // wave col (0..1)
    const int m0 = blockIdx.y * 128;
    const int n0 = blockIdx.x * 128;

    f32x4 acc[4][4];
#pragma unroll
    for (int ti = 0; ti < 4; ++ti)
#pragma unroll
        for (int tj = 0; tj < 4; ++tj)
            acc[ti][tj] = (f32x4){0.f, 0.f, 0.f, 0.f};

    const int kg  = lane >> 4;       // 0..3
    const int rin = lane & 15;       // row within 16-row subtile

    // DMA source coords for this thread's slots (it=0: slot=tid, it=1: +256).
    // slot=tid+256: row += 64, kgroup unchanged (16 = 0 mod 4).
    const int rS = ((tid >> 6) << 4) | (tid & 15);
    const int gS = (tid >> 4) & 3;
    const unsigned short* ga0 = A + (size_t)(m0 + rS) * K + gS * 8;
    const unsigned short* ga1 = A + (size_t)(m0 + rS + 64) * K + gS * 8;
    const unsigned short* gw0 = W + (size_t)(n0 + rS) * K + gS * 8;
    const unsigned short* gw1 = W + (size_t)(n0 + rS + 64) * K + gS * 8;
    short* la0 = &Asl[tid * 8];
    short* la1 = &Asl[(tid + 256) * 8];
    short* lw0 = &Wsl[tid * 8];
    short* lw1 = &Wsl[(tid + 256) * 8];

    for (int k0 = 0; k0 < K; k0 += 32) {
        __syncthreads();             // prev iteration's frag reads complete
        load_lds16(ga0 + k0, la0);
        load_lds16(ga1 + k0, la1);
        load_lds16(gw0 + k0, lw0);
        load_lds16(gw1 + k0, lw1);
        __syncthreads();             // drains vmcnt -> DMA data visible

        short8 af[4], wf[4];
#pragma unroll
        for (int s = 0; s < 4; ++s) {
            af[s] = *(const short8*)&Asl[(((wm * 4 + s) * 4 + kg) * 16 + rin) * 8];
            wf[s] = *(const short8*)&Wsl[(((wn * 4 + s) * 4 + kg) * 16 + rin) * 8];
        }
#pragma unroll
        for (int ti = 0; ti < 4; ++ti)
#pragma unroll
            for (int tj = 0; tj < 4; ++tj)
                acc[ti][tj] = __builtin_amdgcn_mfma_f32_16x16x32_bf16(
                    af[ti], wf[tj], acc[ti][tj], 0, 0, 0);
    }

    // epilogue: D col=lane&15, row=(lane>>4)*4+reg
    const int col0 = n0 + wn * 64 + rin;
    const int row0 = m0 + wm * 64 + kg * 4;
#pragma unroll
    for (int ti = 0; ti < 4; ++ti)
#pragma unroll
        for (int tj = 0; tj < 4; ++tj)
#pragma unroll
            for (int q = 0; q < 4; ++q)
                C[(size_t)(row0 + ti * 16 + q) * ldc + col0 + tj * 16] = acc[ti][tj][q];
}

// ---------------------------------------------------------------------------
// Generic fp32 GEMM (kept for the small delta GEMM): C = A @ W^T, EPI 1 =
// softplus(acc + bias[col]).
// ---------------------------------------------------------------------------
template <int EPI>
__global__ __launch_bounds__(256, 2)
void gemm_tile128(const float* __restrict__ A, int lda,
                  const float* __restrict__ W, int ldw,
                  float* __restrict__ C, int ldc,
                  int K, const float* __restrict__ bias)
{
    __shared__ float As[32][132];
    __shared__ float Ws[32][132];

    const int tid = threadIdx.x;
    const int tx = tid & 15;
    const int ty = tid >> 4;
    const int m0 = blockIdx.y * 128;
    const int n0 = blockIdx.x * 128;

    float acc[2][2][4][4];
#pragma unroll
    for (int im = 0; im < 2; ++im)
#pragma unroll
        for (int jm = 0; jm < 2; ++jm)
#pragma unroll
            for (int i = 0; i < 4; ++i)
#pragma unroll
                for (int j = 0; j < 4; ++j) acc[im][jm][i][j] = 0.f;

    for (int k0 = 0; k0 < K; k0 += 32) {
#pragma unroll
        for (int i = 0; i < 4; ++i) {
            const int idx = tid + i * 256;
            const int r  = idx >> 3;
            const int c4 = idx & 7;
            const float4 va = *(const float4*)(A + (size_t)(m0 + r) * lda + (k0 + c4 * 4));
            As[c4 * 4 + 0][r] = va.x;
            As[c4 * 4 + 1][r] = va.y;
            As[c4 * 4 + 2][r] = va.z;
            As[c4 * 4 + 3][r] = va.w;
            const float4 vw = *(const float4*)(W + (size_t)(n0 + r) * ldw + (k0 + c4 * 4));
            Ws[c4 * 4 + 0][r] = vw.x;
            Ws[c4 * 4 + 1][r] = vw.y;
            Ws[c4 * 4 + 2][r] = vw.z;
            Ws[c4 * 4 + 3][r] = vw.w;
        }
        __syncthreads();

#pragma unroll
        for (int kk = 0; kk < 32; ++kk) {
            float a[2][4], bfr[2][4];
            *(float4*)&a[0][0]   = *(const float4*)&As[kk][ty * 4];
            *(float4*)&a[1][0]   = *(const float4*)&As[kk][64 + ty * 4];
            *(float4*)&bfr[0][0] = *(const float4*)&Ws[kk][tx * 4];
            *(float4*)&bfr[1][0] = *(const float4*)&Ws[kk][64 + tx * 4];
#pragma unroll
            for (int im = 0; im < 2; ++im)
#pragma unroll
                for (int i = 0; i < 4; ++i)
#pragma unroll
                    for (int jm = 0; jm < 2; ++jm)
#pragma unroll
                        for (int j = 0; j < 4; ++j)
                            acc[im][jm][i][j] = fmaf(a[im][i], bfr[jm][j], acc[im][jm][i][j]);
        }
        __syncthreads();
    }

#pragma unroll
    for (int im = 0; im < 2; ++im) {
#pragma unroll
        for (int i = 0; i < 4; ++i) {
            const int row = m0 + im * 64 + ty * 4 + i;
#pragma unroll
            for (int jm = 0; jm < 2; ++jm) {
                const int col = n0 + jm * 64 + tx * 4;
                float4 v;
                v.x = acc[im][jm][i][0];
                v.y = acc[im][jm][i][1];
                v.z = acc[im][jm][i][2];
                v.w = acc[im][jm][i][3];
                if (EPI == 1) {
                    v.x = softplusf(v.x + bias[col + 0]);
                    v.y = softplusf(v.y + bias[col + 1]);
                    v.z = softplusf(v.z + bias[col + 2]);
                    v.w = softplusf(v.w + bias[col + 3]);
                }
                *(float4*)(C + (size_t)row * ldc + col) = v;
            }
        }
    }
}

// ---------------------------------------------------------------------------
// Depthwise causal conv1d (taps=4, left pad 3) + silu.
// ---------------------------------------------------------------------------
__global__ __launch_bounds__(256)
void conv_silu_kernel(const float* __restrict__ xz,
                      const float* __restrict__ cw,
                      const float* __restrict__ cb,
                      float* __restrict__ xssm)
{
    const int idx = blockIdx.x * 256 + threadIdx.x;
    const int d  = idx & (D_INNER - 1);
    const int bt = idx >> 11;
    const int t  = bt & (SEQ - 1);
    const float* p = xz + (size_t)bt * 4096 + d;
    const float w0 = cw[d * 4 + 0], w1 = cw[d * 4 + 1];
    const float w2 = cw[d * 4 + 2], w3 = cw[d * 4 + 3];
    float acc = cb[d] + w3 * p[0];
    if (t >= 1) acc += w2 * p[-4096];
    if (t >= 2) acc += w1 * p[-8192];
    if (t >= 3) acc += w0 * p[-12288];
    xssm[idx] = siluf(acc);
}

// ---------------------------------------------------------------------------
// proj split-K pass 1: partial[ks][m][96] = x_ssm[m, ks*256:(ks+1)*256] @ W^T
// Grid (M/64, KS) = 512 blocks; BM=64, BN=96, BK=32 inner.
// ---------------------------------------------------------------------------
__global__ __launch_bounds__(256, 2)
void gemm_proj_splitk(const float* __restrict__ A,
                      const float* __restrict__ W,
                      float* __restrict__ partial)
{
    __shared__ float As[32][68];
    __shared__ float Ws[32][100];
    const int tid = threadIdx.x;
    const int tx = tid & 15;
    const int ty = tid >> 4;
    const int m0 = blockIdx.x * 64;
    const int ks = blockIdx.y;

    float acc[4][6];
#pragma unroll
    for (int i = 0; i < 4; ++i)
#pragma unroll
        for (int j = 0; j < 6; ++j) acc[i][j] = 0.f;

    for (int k0 = ks * KCH; k0 < (ks + 1) * KCH; k0 += 32) {
#pragma unroll
        for (int i = 0; i < 2; ++i) {               // A: 64x32 = 512 float4
            const int idx = tid + i * 256;
            const int r = idx >> 3, c4 = idx & 7;
            const float4 v = *(const float4*)(A + (size_t)(m0 + r) * 2048 + k0 + c4 * 4);
            As[c4 * 4 + 0][r] = v.x;
            As[c4 * 4 + 1][r] = v.y;
            As[c4 * 4 + 2][r] = v.z;
            As[c4 * 4 + 3][r] = v.w;
        }
#pragma unroll
        for (int i = 0; i < 3; ++i) {               // W: 96x32 = 768 float4
            const int idx = tid + i * 256;
            const int r = idx >> 3, c4 = idx & 7;
            const float4 v = *(const float4*)(W + (size_t)r * 2048 + k0 + c4 * 4);
            Ws[c4 * 4 + 0][r] = v.x;
            Ws[c4 * 4 + 1][r] = v.y;
            Ws[c4 * 4 + 2][r] = v.z;
            Ws[c4 * 4 + 3][r] = v.w;
        }
        __syncthreads();
#pragma unroll
        for (int kk = 0; kk < 32; ++kk) {
            float a[4];
            *(float4*)a = *(const float4*)&As[kk][ty * 4];
            float bv[6];
#pragma unroll
            for (int j = 0; j < 6; ++j) bv[j] = Ws[kk][tx * 6 + j];
#pragma unroll
            for (int i = 0; i < 4; ++i)
#pragma unroll
                for (int j = 0; j < 6; ++j) acc[i][j] = fmaf(a[i], bv[j], acc[i][j]);
        }
        __syncthreads();
    }

    float* outp = partial + (size_t)ks * M_ROWS * 96;
#pragma unroll
    for (int i = 0; i < 4; ++i)
#pragma unroll
        for (int j = 0; j < 6; ++j)
            outp[(size_t)(m0 + ty * 4 + i) * 96 + tx * 6 + j] = acc[i][j];
}

// proj split-K pass 2: proj[idx] = sum_ks partial[ks][idx]
__global__ __launch_bounds__(256)
void proj_reduce(const float* __restrict__ partial, float* __restrict__ proj)
{
    const int idx = blockIdx.x * 256 + threadIdx.x;   // over M_ROWS*96
    float s = 0.f;
#pragma unroll
    for (int ks = 0; ks < KS; ++ks)
        s += partial[(size_t)ks * M_ROWS * 96 + idx];
    proj[idx] = s;
}

// ---------------------------------------------------------------------------
// Chunked parallel selective scan (see Round-2 notes). pass3 emits y directly
// as bf16 for the out-projection MFMA GEMM.
// ---------------------------------------------------------------------------
__global__ __launch_bounds__(256)
void scan_pass1(const float* __restrict__ delta,
                const float* __restrict__ xssm,
                const float* __restrict__ proj,
                const float* __restrict__ A_log,
                float* __restrict__ Pbuf,
                float* __restrict__ Qbuf)
{
    const int c = blockIdx.x;
    const int b = blockIdx.z;
    const int d = blockIdx.y * 256 + threadIdx.x;

    float Areg[16], P[16], Q[16];
    const float4* arow = (const float4*)(A_log + (size_t)d * 16);
#pragma unroll
    for (int q = 0; q < 4; ++q) {
        const float4 v = arow[q];
        Areg[q * 4 + 0] = -__expf(v.x);
        Areg[q * 4 + 1] = -__expf(v.y);
        Areg[q * 4 + 2] = -__expf(v.z);
        Areg[q * 4 + 3] = -__expf(v.w);
    }
#pragma unroll
    for (int n = 0; n < 16; ++n) { P[n] = 1.f; Q[n] = 0.f; }

    const float* dl = delta + ((size_t)b * SEQ + c * TC) * D_INNER + d;
    const float* up = xssm  + ((size_t)b * SEQ + c * TC) * D_INNER + d;
    const float* pr = proj  + ((size_t)b * SEQ + c * TC) * 96 + 64;

#pragma unroll 4
    for (int i = 0; i < TC; ++i) {
        const float dlv = dl[(size_t)i * D_INNER];
        const float uv  = up[(size_t)i * D_INNER];
        const float du  = dlv * uv;
        const float* prt = pr + i * 96;
#pragma unroll
        for (int n = 0; n < 16; ++n) {
            const float dA = __expf(dlv * Areg[n]);
            Q[n] = fmaf(dA, Q[n], du * prt[n]);
            P[n] *= dA;
        }
    }

    const size_t base = (((size_t)b * NC + c) * 16) * D_INNER + d;
#pragma unroll
    for (int n = 0; n < 16; ++n) {
        Pbuf[base + (size_t)n * D_INNER] = P[n];
        Qbuf[base + (size_t)n * D_INNER] = Q[n];
    }
}

__global__ __launch_bounds__(256)
void scan_pass2(const float* __restrict__ Pbuf,
                float* __restrict__ Qbuf)
{
    const int i = blockIdx.x * 256 + threadIdx.x;
    const int d = i & (D_INNER - 1);
    const int n = (i >> 11) & 15;
    const int b = i >> 15;

    float hs = 0.f;
    const size_t stride = (size_t)16 * D_INNER;
    size_t idx = ((size_t)b * NC * 16 + n) * D_INNER + d;
    for (int c = 0; c < NC; ++c) {
        const float Pv = Pbuf[idx];
        const float Qv = Qbuf[idx];
        Qbuf[idx] = hs;
        hs = fmaf(Pv, hs, Qv);
        idx += stride;
    }
}

__global__ __launch_bounds__(256)
void scan_pass3(const float* __restrict__ delta,
                const float* __restrict__ xssm,
                const float* __restrict__ proj,
                const float* __restrict__ xz,
                const float* __restrict__ A_log,
                const float* __restrict__ Dvec,
                const float* __restrict__ Qbuf,
                unsigned short* __restrict__ ybf)
{
    const int c = blockIdx.x;
    const int b = blockIdx.z;
    const int d = blockIdx.y * 256 + threadIdx.x;

    float Areg[16], h[16];
    const float4* arow = (const float4*)(A_log + (size_t)d * 16);
#pragma unroll
    for (int q = 0; q < 4; ++q) {
        const float4 v = arow[q];
        Areg[q * 4 + 0] = -__expf(v.x);
        Areg[q * 4 + 1] = -__expf(v.y);
        Areg[q * 4 + 2] = -__expf(v.z);
        Areg[q * 4 + 3] = -__expf(v.w);
    }
    const size_t hbase = (((size_t)b * NC + c) * 16) * D_INNER + d;
#pragma unroll
    for (int n = 0; n < 16; ++n) h[n] = Qbuf[hbase + (size_t)n * D_INNER];

    const float Dd = Dvec[d];
    const float* dlp = delta + ((size_t)b * SEQ + c * TC) * D_INNER + d;
    const float* up  = xssm  + ((size_t)b * SEQ + c * TC) * D_INNER + d;
    const float* zp  = xz    + ((size_t)b * SEQ + c * TC) * 4096 + 2048 + d;
    const float* pr  = proj  + ((size_t)b * SEQ + c * TC) * 96 + 64;
    unsigned short* yp = ybf + ((size_t)b * SEQ + c * TC) * D_INNER + d;

#pragma unroll 4
    for (int i = 0; i < TC; ++i) {
        const float dlv = dlp[(size_t)i * D_INNER];
        const float uv  = up[(size_t)i * D_INNER];
        const float zv  = zp[(size_t)i * 4096];
        const float du  = dlv * uv;
        const float* prt = pr + i * 96;
        float ysum = 0.f;
#pragma unroll
        for (int n = 0; n < 16; ++n) {
            const float dA = __expf(dlv * Areg[n]);
            h[n] = fmaf(dA, h[n], du * prt[n]);
            ysum = fmaf(h[n], prt[16 + n], ysum);
        }
        yp[(size_t)i * D_INNER] = f2bf((ysum + uv * Dd) * siluf(zv));
    }
}

// ---------------------------------------------------------------------------
// Workspace layout (162 MB total == bound proven by Round-2/7/9 passes):
//   [  0..64 )  xz      fp32 M x 4096        live steps 1-5c
//   [ 64..96 )  xssm    fp32 M x 2048        live steps 2-5c
//   [ 96..98 )  proj    fp32 M x 96          live steps 3b-5c
//   [ 98..130)  delta   fp32 M x 2048        live steps 4-5c
//   [130..146)  xb(0-1) | partial(3a-3b) | Pbuf(5a-5b) | ybf(5c-6)   disjoint
//   [146..162)  wbi(0-1) | Qbuf(5a-5c) | wbo(post-5c..6)             disjoint
// ---------------------------------------------------------------------------
extern "C" void kernel_launch(void* const* d_in, const int* in_sizes, int n_in,
                              void* d_out, int out_size, void* d_ws, size_t ws_size,
                              hipStream_t stream)
{
    const float* x          = (const float*)d_in[0];
    const float* in_proj_w  = (const float*)d_in[1];
    const float* conv_w     = (const float*)d_in[2];
    const float* conv_b     = (const float*)d_in[3];
    const float* x_proj_w   = (const float*)d_in[4];
    const float* dt_proj_w  = (const float*)d_in[5];
    const float* dt_proj_b  = (const float*)d_in[6];
    const float* A_log      = (const float*)d_in[7];
    const float* Dvec       = (const float*)d_in[8];
    const float* out_proj_w = (const float*)d_in[9];
    float* out = (float*)d_out;

    char* ws = (char*)d_ws;
    const size_t MB = 1024 * 1024;
    float* xz    = (float*)(ws);
    float* xssm  = (float*)(ws + 64  * MB);
    float* proj  = (float*)(ws + 96  * MB);
    float* delta = (float*)(ws + 98  * MB);
    unsigned short* xb      = (unsigned short*)(ws + 130 * MB);  // steps 0-1
    float*          partial = (float*)(ws + 130 * MB);           // steps 3a-3b
    float*          Pbuf    = (float*)(ws + 130 * MB);           // steps 5a-5b
    unsigned short* ybf     = (unsigned short*)(ws + 130 * MB);  // steps 5c-6
    unsigned short* wbi     = (unsigned short*)(ws + 146 * MB);  // steps 0-1
    float*          Qbuf    = (float*)(ws + 146 * MB);           // steps 5a-5c
    unsigned short* wbo     = (unsigned short*)(ws + 146 * MB);  // post-5c..6

    const dim3 blk(256);

    // 0) pre-convert bf16 operands for GEMM1
    cvt_f32_bf16<<<dim3((M_ROWS * D_MODEL) / (256 * 8)), blk, 0, stream>>>(x, xb);
    cvt_f32_bf16<<<dim3((2 * D_INNER * D_MODEL) / (256 * 8)), blk, 0, stream>>>(in_proj_w, wbi);

    // 1) xz = x @ in_proj_w^T                (M x 4096, bf16 MFMA)
    gemm_bf16<<<dim3(4096 / 128, M_ROWS / 128), blk, 0, stream>>>(
        xb, wbi, xz, 2 * D_INNER, D_MODEL);

    // 2) x_ssm = silu(causal_conv1d(x_in))   (M x 2048)
    conv_silu_kernel<<<dim3((M_ROWS * D_INNER) / 256), blk, 0, stream>>>(
        xz, conv_w, conv_b, xssm);

    // 3) proj = x_ssm @ x_proj_w^T           (M x 96, fp32 split-K)
    gemm_proj_splitk<<<dim3(M_ROWS / 64, KS), blk, 0, stream>>>(xssm, x_proj_w, partial);
    proj_reduce<<<dim3((M_ROWS * 96) / 256), blk, 0, stream>>>(partial, proj);

    // 4) delta = softplus(dt @ dt_proj_w^T + b)  (M x 2048, fp32)
    gemm_tile128<1><<<dim3(D_INNER / 128, M_ROWS / 128), blk, 0, stream>>>(
        proj, 96, dt_proj_w, DT_RANK, delta, D_INNER, DT_RANK, dt_proj_b);

    // 5) chunked parallel scan (fused skip + gate), y emitted as bf16
    scan_pass1<<<dim3(NC, D_INNER / 256, BATCH), blk, 0, stream>>>(
        delta, xssm, proj, A_log, Pbuf, Qbuf);
    scan_pass2<<<dim3((BATCH * D_INNER * 16) / 256), blk, 0, stream>>>(Pbuf, Qbuf);
    scan_pass3<<<dim3(NC, D_INNER / 256, BATCH), blk, 0, stream>>>(
        delta, xssm, proj, xz, A_log, Dvec, Qbuf, ybf);

    // 5d) out_proj_w -> bf16 (Qbuf region is dead now; stream-ordered alias)
    cvt_f32_bf16<<<dim3((D_MODEL * D_INNER) / (256 * 8)), blk, 0, stream>>>(out_proj_w, wbo);

    // 6) out = y @ out_proj_w^T              (M x 1024, bf16 MFMA)
    gemm_bf16<<<dim3(D_MODEL / 128, M_ROWS / 128), blk, 0, stream>>>(
        ybf, wbo, out, D_MODEL, D_INNER);
}